// Round 3
// baseline (1669.671 us; speedup 1.0000x reference)
//
#include <hip/hip_runtime.h>
#include <math.h>

#define NROWS 131072
#define SDIM 64
#define HDIM 128
#define KCODES 512
#define ADIM 8
// LDS row stride in floats: 132*4=528 B -> 16B-aligned rows (ds_read_b128 ok),
// 132%32==4 -> consecutive rows shift banks by 4 (benign aliasing).
#define LSTR 132

// ---------------------------------------------------------------------------
// k0: ee[k] = sum_j emb[k][j]^2   (exact FP order from rounds 1-2, absmax 0)
// ---------------------------------------------------------------------------
__global__ void ee_kernel(const float* __restrict__ emb, float* __restrict__ ee) {
    int k = blockIdx.x * blockDim.x + threadIdx.x;
    if (k >= KCODES) return;
    const float* e = emb + k * HDIM;
    float a0 = 0.f, a1 = 0.f, a2 = 0.f, a3 = 0.f;
#pragma unroll
    for (int j = 0; j < HDIM; j += 4) {
        a0 = fmaf(e[j + 0], e[j + 0], a0);
        a1 = fmaf(e[j + 1], e[j + 1], a1);
        a2 = fmaf(e[j + 2], e[j + 2], a2);
        a3 = fmaf(e[j + 3], e[j + 3], a3);
    }
    ee[k] = (a0 + a1) + (a2 + a3);
}

// ---------------------------------------------------------------------------
// Fully fused: input->LDS, MLP (x2 into private LDS row), VQ score (x via
// ds_read_b128, emb via uniform s_load), argmin, heads, output.
// 128 threads/block, 1024 blocks. LDS 69.6 KB -> 2 blocks/CU.
// __launch_bounds__(128,2): VGPR cap 256 (need ~150 for accA+accB live).
// ---------------------------------------------------------------------------
__global__ __launch_bounds__(128, 2) void fused_kernel(
    const float* __restrict__ in,
    const float* __restrict__ W1, const float* __restrict__ b1,
    const float* __restrict__ Wh, const float* __restrict__ bh,
    const float* __restrict__ emb,
    const float* __restrict__ Wa, const float* __restrict__ ba,
    const float* __restrict__ Wv, const float* __restrict__ bv,
    const float* __restrict__ ee_g,   // precomputed ||e||^2 in ws (may be null)
    float* __restrict__ out)
{
    __shared__ float lds[128 * LSTR];
    __shared__ float ee_s[KCODES];
    const int tid = threadIdx.x;
    const int base = blockIdx.x * 128;

    // --- stage ee into LDS (copy from ws, or compute if no ws) ---
    if (ee_g != nullptr) {
        ((float4*)ee_s)[tid] = ((const float4*)ee_g)[tid];   // 512 floats, 4/thread
    } else {
#pragma unroll
        for (int kk = 0; kk < 4; ++kk) {
            int k = tid + 128 * kk;
            const float* e = emb + k * HDIM;
            float a0 = 0.f, a1 = 0.f, a2 = 0.f, a3 = 0.f;
#pragma unroll
            for (int j = 0; j < HDIM; j += 4) {
                a0 = fmaf(e[j + 0], e[j + 0], a0);
                a1 = fmaf(e[j + 1], e[j + 1], a1);
                a2 = fmaf(e[j + 2], e[j + 2], a2);
                a3 = fmaf(e[j + 3], e[j + 3], a3);
            }
            ee_s[k] = (a0 + a1) + (a2 + a3);
        }
    }

    // --- phase A: coalesced stage of 128x64 input tile ---
    const float* src = in + (size_t)base * SDIM;
#pragma unroll
    for (int it = 0; it < 64; ++it) {
        int i = tid + 128 * it;       // 0..8191
        int r = i >> 6, c = i & 63;
        lds[r * LSTR + c] = src[i];
    }
    __syncthreads();

    float* myrow = &lds[tid * LSTR];

    // --- phase B chunk0: x1[0..63] -> cols 64..127 ---
    {
        float acc[64];
#pragma unroll
        for (int j = 0; j < 64; ++j) acc[j] = b1[j];
        for (int s = 0; s < SDIM; ++s) {
            float a = myrow[s];
#pragma unroll
            for (int j = 0; j < 64; ++j) acc[j] = fmaf(a, W1[s * HDIM + j], acc[j]);
        }
#pragma unroll
        for (int j = 0; j < 64; ++j) myrow[64 + j] = fmaxf(acc[j], 0.f);
    }
    // --- phase B chunk1: x1[64..127] -> cols 0..63 ---
    {
        float acc[64];
#pragma unroll
        for (int j = 0; j < 64; ++j) acc[j] = b1[64 + j];
        for (int s = 0; s < SDIM; ++s) {
            float a = myrow[s];
#pragma unroll
            for (int j = 0; j < 64; ++j) acc[j] = fmaf(a, W1[s * HDIM + 64 + j], acc[j]);
        }
#pragma unroll
        for (int j = 0; j < 64; ++j) myrow[j] = fmaxf(acc[j], 0.f);
    }

    // --- phase C: x2 = relu(x1 @ Wh + bh); both 64-chunks resident, then
    // write back to myrow[0..127] (x1 fully consumed first). t = 0..127 asc.
    {
        float accA[64], accB[64];
#pragma unroll
        for (int j = 0; j < 64; ++j) accA[j] = bh[j];
#pragma unroll
        for (int j = 0; j < 64; ++j) accB[j] = bh[64 + j];
        for (int t = 0; t < 64; ++t) {
            float a = myrow[64 + t];      // x1[t]
#pragma unroll
            for (int j = 0; j < 64; ++j) accA[j] = fmaf(a, Wh[t * HDIM + j], accA[j]);
#pragma unroll
            for (int j = 0; j < 64; ++j) accB[j] = fmaf(a, Wh[t * HDIM + 64 + j], accB[j]);
        }
        for (int t = 0; t < 64; ++t) {
            float a = myrow[t];           // x1[64+t]
#pragma unroll
            for (int j = 0; j < 64; ++j) accA[j] = fmaf(a, Wh[(64 + t) * HDIM + j], accA[j]);
#pragma unroll
            for (int j = 0; j < 64; ++j) accB[j] = fmaf(a, Wh[(64 + t) * HDIM + 64 + j], accB[j]);
        }
#pragma unroll
        for (int j = 0; j < 64; ++j) myrow[j] = fmaxf(accA[j], 0.f);
#pragma unroll
        for (int j = 0; j < 64; ++j) myrow[64 + j] = fmaxf(accB[j], 0.f);
    }
    // myrow is thread-private: no barrier needed before reading it back.

    const float4* xr4 = (const float4*)myrow;   // tid*528 B: 16B-aligned

    // --- vv = ||x||^2, same 4-way split/order as rounds 1-2 ---
    float v0 = 0.f, v1 = 0.f, v2 = 0.f, v3 = 0.f;
#pragma unroll
    for (int j4 = 0; j4 < 32; ++j4) {
        float4 q = xr4[j4];
        v0 = fmaf(q.x, q.x, v0);
        v1 = fmaf(q.y, q.y, v1);
        v2 = fmaf(q.z, q.z, v2);
        v3 = fmaf(q.w, q.w, v3);
    }
    const float vv = (v0 + v1) + (v2 + v3);

    // --- VQ scoring: 8 codes per group, j ascending 0..127 per code ---
    float best = 3.402823466e38f;
    int bi = 0;
    for (int k0 = 0; k0 < KCODES; k0 += 8) {
        const float* eb = emb + (size_t)k0 * HDIM;
        float d[8];
#pragma unroll
        for (int c = 0; c < 8; ++c) d[c] = 0.f;
#pragma unroll 8
        for (int j4 = 0; j4 < 32; ++j4) {
            float4 q = xr4[j4];              // ds_read_b128, offset imm
            const float* ej = eb + 4 * j4;   // wave-uniform -> s_load operands
#pragma unroll
            for (int c = 0; c < 8; ++c) {
                float t = d[c];
                t = fmaf(q.x, ej[c * HDIM + 0], t);
                t = fmaf(q.y, ej[c * HDIM + 1], t);
                t = fmaf(q.z, ej[c * HDIM + 2], t);
                t = fmaf(q.w, ej[c * HDIM + 3], t);
                d[c] = t;
            }
        }
#pragma unroll
        for (int c = 0; c < 8; ++c) {
            const float dd = (vv - 2.f * d[c]) + ee_s[k0 + c];
            if (dd < best) { best = dd; bi = k0 + c; }   // strict <: first wins
        }
    }

    // --- heads: quantize = emb[bi]; exact FP order of rounds 1-2 ---
    float lg[ADIM];
#pragma unroll
    for (int a = 0; a < ADIM; ++a) lg[a] = ba[a];
    float val = bv[0];

    const float4* q4 = (const float4*)(emb + (size_t)bi * HDIM);
#pragma unroll
    for (int j4 = 0; j4 < HDIM / 4; ++j4) {
        float4 q = q4[j4];
        const int j = 4 * j4;
#pragma unroll
        for (int a = 0; a < ADIM; ++a) {
            float t = lg[a];
            t = fmaf(q.x, Wa[(j + 0) * ADIM + a], t);
            t = fmaf(q.y, Wa[(j + 1) * ADIM + a], t);
            t = fmaf(q.z, Wa[(j + 2) * ADIM + a], t);
            t = fmaf(q.w, Wa[(j + 3) * ADIM + a], t);
            lg[a] = t;
        }
        val = fmaf(q.x, Wv[j + 0], val);
        val = fmaf(q.y, Wv[j + 1], val);
        val = fmaf(q.z, Wv[j + 2], val);
        val = fmaf(q.w, Wv[j + 3], val);
    }

    float m = lg[0];
#pragma unroll
    for (int a = 1; a < ADIM; ++a) m = fmaxf(m, lg[a]);
    float p[ADIM];
    float s = 0.f;
#pragma unroll
    for (int a = 0; a < ADIM; ++a) { p[a] = __expf(lg[a] - m); s += p[a]; }
    const float inv = 1.f / s;

    const int row = base + tid;
    float4* outp = (float4*)(out + (size_t)row * ADIM);
    outp[0] = make_float4(p[0] * inv, p[1] * inv, p[2] * inv, p[3] * inv);
    outp[1] = make_float4(p[4] * inv, p[5] * inv, p[6] * inv, p[7] * inv);
    out[(size_t)NROWS * ADIM + row] = val;
}

// ---------------------------------------------------------------------------
extern "C" void kernel_launch(void* const* d_in, const int* in_sizes, int n_in,
                              void* d_out, int out_size, void* d_ws, size_t ws_size,
                              hipStream_t stream) {
    const float* in  = (const float*)d_in[0];
    const float* W1  = (const float*)d_in[1];
    const float* b1  = (const float*)d_in[2];
    const float* Wh  = (const float*)d_in[3];
    const float* bh  = (const float*)d_in[4];
    const float* emb = (const float*)d_in[5];
    const float* Wa  = (const float*)d_in[6];
    const float* ba  = (const float*)d_in[7];
    const float* Wv  = (const float*)d_in[8];
    const float* bv  = (const float*)d_in[9];
    float* out = (float*)d_out;

    const float* ee = nullptr;
    if (ws_size >= KCODES * sizeof(float)) {
        ee_kernel<<<2, 256, 0, stream>>>(emb, (float*)d_ws);
        ee = (const float*)d_ws;
    }
    fused_kernel<<<NROWS / 128, 128, 0, stream>>>(in, W1, b1, Wh, bh, emb,
                                                  Wa, ba, Wv, bv, ee, out);
}

// Round 4
// 948.483 us; speedup vs baseline: 1.7604x; 1.7604x over previous
//
#include <hip/hip_runtime.h>
#include <math.h>

#define NROWS 131072
#define SDIM 64
#define HDIM 128
#define KCODES 512
#define ADIM 8

// Macro repetition: all per-thread "arrays" are named float4 vars, indexed
// ONLY by compile-time constants -> compiler cannot demote to scratch or
// rematerialize from memory (the round-1/2/3 failure modes).
#define R16(M) M(0) M(1) M(2) M(3) M(4) M(5) M(6) M(7) \
               M(8) M(9) M(10) M(11) M(12) M(13) M(14) M(15)
#define R32(M) R16(M) M(16) M(17) M(18) M(19) M(20) M(21) M(22) M(23) \
               M(24) M(25) M(26) M(27) M(28) M(29) M(30) M(31)

// ---------------------------------------------------------------------------
// w1t[t][s] = W1[s][t]  (32 KB) so layer-1 weight reads are consecutive
// wave-uniform runs -> s_load_dwordx16.
// ---------------------------------------------------------------------------
__global__ void w1t_kernel(const float* __restrict__ W1, float* __restrict__ w1t) {
    int i = blockIdx.x * 256 + threadIdx.x;        // 0..8191, == t*64+s
    int t = i >> 6, s = i & 63;
    w1t[i] = W1[s * HDIM + t];
}

// ---------------------------------------------------------------------------
// Fully fused, register-resident. 256 thr/block, 512 blocks.
// LDS: ee_s only (2 KB). VGPR peak ~210 -> 2 waves/SIMD via launch_bounds.
// FP chain orders identical to rounds 1-3 (absmax 0.0):
//   x1[t]: s ascending 0..63 single chain; x2[j]: t ascending 0..127;
//   vv: 4-way by j%4; dot_k: j ascending; heads/softmax unchanged.
// ---------------------------------------------------------------------------
__global__ __launch_bounds__(256, 2) void fused_kernel(
    const float* __restrict__ in,
    const float* __restrict__ W1, const float* __restrict__ w1t,  // w1t may be null
    const float* __restrict__ b1,
    const float* __restrict__ Wh, const float* __restrict__ bh,
    const float* __restrict__ emb,
    const float* __restrict__ Wa, const float* __restrict__ ba,
    const float* __restrict__ Wv, const float* __restrict__ bv,
    float* __restrict__ out)
{
    __shared__ float ee_s[KCODES];
    const int tid = threadIdx.x;
    const int row = blockIdx.x * 256 + tid;

    // --- ee: 2 codes per thread, exact ee_kernel FP order ---
#pragma unroll
    for (int kk = 0; kk < 2; ++kk) {
        int k = tid + 256 * kk;
        const float* e = emb + k * HDIM;
        float a0 = 0.f, a1 = 0.f, a2 = 0.f, a3 = 0.f;
#pragma unroll
        for (int j = 0; j < HDIM; j += 4) {
            a0 = fmaf(e[j + 0], e[j + 0], a0);
            a1 = fmaf(e[j + 1], e[j + 1], a1);
            a2 = fmaf(e[j + 2], e[j + 2], a2);
            a3 = fmaf(e[j + 3], e[j + 3], a3);
        }
        ee_s[k] = (a0 + a1) + (a2 + a3);
    }
    __syncthreads();

    // --- input row into 16 named float4s ---
    const float4* inr4 = (const float4*)(in + (size_t)row * SDIM);
#define DECLI(n) float4 i##n = inr4[n];
    R16(DECLI)

    // --- x2 accumulators: 32 named float4s, init = bh ---
#define DECLX(m) float4 x##m = make_float4(bh[4*(m)+0], bh[4*(m)+1], bh[4*(m)+2], bh[4*(m)+3]);
    R32(DECLX)

    // --- fused layer1+layer2: x1[t] scalar then rank-1 update of x2 ---
#define L1T(n) xt = fmaf(i##n.x, wr[4*(n)+0], xt); xt = fmaf(i##n.y, wr[4*(n)+1], xt); \
               xt = fmaf(i##n.z, wr[4*(n)+2], xt); xt = fmaf(i##n.w, wr[4*(n)+3], xt);
#define L1N(n) xt = fmaf(i##n.x, wc[(4*(n)+0)*HDIM], xt); xt = fmaf(i##n.y, wc[(4*(n)+1)*HDIM], xt); \
               xt = fmaf(i##n.z, wc[(4*(n)+2)*HDIM], xt); xt = fmaf(i##n.w, wc[(4*(n)+3)*HDIM], xt);
#define L2(m)  x##m.x = fmaf(xt, whr[4*(m)+0], x##m.x); x##m.y = fmaf(xt, whr[4*(m)+1], x##m.y); \
               x##m.z = fmaf(xt, whr[4*(m)+2], x##m.z); x##m.w = fmaf(xt, whr[4*(m)+3], x##m.w);
    if (w1t != nullptr) {
        for (int t = 0; t < HDIM; ++t) {
            float xt = b1[t];
            const float* wr = w1t + t * SDIM;
            R16(L1T)
            xt = fmaxf(xt, 0.f);                 // relu(x1[t])
            const float* whr = Wh + t * HDIM;
            R32(L2)
        }
    } else {
        for (int t = 0; t < HDIM; ++t) {
            float xt = b1[t];
            const float* wc = W1 + t;
            R16(L1N)
            xt = fmaxf(xt, 0.f);
            const float* whr = Wh + t * HDIM;
            R32(L2)
        }
    }

    // --- relu(x2) ---
#define RELUX(m) x##m.x = fmaxf(x##m.x, 0.f); x##m.y = fmaxf(x##m.y, 0.f); \
                 x##m.z = fmaxf(x##m.z, 0.f); x##m.w = fmaxf(x##m.w, 0.f);
    R32(RELUX)

    // --- vv = ||x||^2, 4-way split by j%4 (exact round-1/2/3 order) ---
    float v0 = 0.f, v1 = 0.f, v2 = 0.f, v3 = 0.f;
#define VV(m) v0 = fmaf(x##m.x, x##m.x, v0); v1 = fmaf(x##m.y, x##m.y, v1); \
              v2 = fmaf(x##m.z, x##m.z, v2); v3 = fmaf(x##m.w, x##m.w, v3);
    R32(VV)
    const float vv = (v0 + v1) + (v2 + v3);

    // --- VQ scoring: 8 codes/group, j ascending per code ---
    float best = 3.402823466e38f;
    int bi = 0;
#define SC(m) \
    d0 = fmaf(x##m.x, eb[0*HDIM+4*(m)+0], d0); d0 = fmaf(x##m.y, eb[0*HDIM+4*(m)+1], d0); \
    d0 = fmaf(x##m.z, eb[0*HDIM+4*(m)+2], d0); d0 = fmaf(x##m.w, eb[0*HDIM+4*(m)+3], d0); \
    d1 = fmaf(x##m.x, eb[1*HDIM+4*(m)+0], d1); d1 = fmaf(x##m.y, eb[1*HDIM+4*(m)+1], d1); \
    d1 = fmaf(x##m.z, eb[1*HDIM+4*(m)+2], d1); d1 = fmaf(x##m.w, eb[1*HDIM+4*(m)+3], d1); \
    d2 = fmaf(x##m.x, eb[2*HDIM+4*(m)+0], d2); d2 = fmaf(x##m.y, eb[2*HDIM+4*(m)+1], d2); \
    d2 = fmaf(x##m.z, eb[2*HDIM+4*(m)+2], d2); d2 = fmaf(x##m.w, eb[2*HDIM+4*(m)+3], d2); \
    d3 = fmaf(x##m.x, eb[3*HDIM+4*(m)+0], d3); d3 = fmaf(x##m.y, eb[3*HDIM+4*(m)+1], d3); \
    d3 = fmaf(x##m.z, eb[3*HDIM+4*(m)+2], d3); d3 = fmaf(x##m.w, eb[3*HDIM+4*(m)+3], d3); \
    d4 = fmaf(x##m.x, eb[4*HDIM+4*(m)+0], d4); d4 = fmaf(x##m.y, eb[4*HDIM+4*(m)+1], d4); \
    d4 = fmaf(x##m.z, eb[4*HDIM+4*(m)+2], d4); d4 = fmaf(x##m.w, eb[4*HDIM+4*(m)+3], d4); \
    d5 = fmaf(x##m.x, eb[5*HDIM+4*(m)+0], d5); d5 = fmaf(x##m.y, eb[5*HDIM+4*(m)+1], d5); \
    d5 = fmaf(x##m.z, eb[5*HDIM+4*(m)+2], d5); d5 = fmaf(x##m.w, eb[5*HDIM+4*(m)+3], d5); \
    d6 = fmaf(x##m.x, eb[6*HDIM+4*(m)+0], d6); d6 = fmaf(x##m.y, eb[6*HDIM+4*(m)+1], d6); \
    d6 = fmaf(x##m.z, eb[6*HDIM+4*(m)+2], d6); d6 = fmaf(x##m.w, eb[6*HDIM+4*(m)+3], d6); \
    d7 = fmaf(x##m.x, eb[7*HDIM+4*(m)+0], d7); d7 = fmaf(x##m.y, eb[7*HDIM+4*(m)+1], d7); \
    d7 = fmaf(x##m.z, eb[7*HDIM+4*(m)+2], d7); d7 = fmaf(x##m.w, eb[7*HDIM+4*(m)+3], d7);
    for (int k0 = 0; k0 < KCODES; k0 += 8) {
        const float* eb = emb + (size_t)k0 * HDIM;
        float d0 = 0.f, d1 = 0.f, d2 = 0.f, d3 = 0.f;
        float d4 = 0.f, d5 = 0.f, d6 = 0.f, d7 = 0.f;
        R32(SC)
        float dd;
        dd = (vv - 2.f * d0) + ee_s[k0 + 0]; if (dd < best) { best = dd; bi = k0 + 0; }
        dd = (vv - 2.f * d1) + ee_s[k0 + 1]; if (dd < best) { best = dd; bi = k0 + 1; }
        dd = (vv - 2.f * d2) + ee_s[k0 + 2]; if (dd < best) { best = dd; bi = k0 + 2; }
        dd = (vv - 2.f * d3) + ee_s[k0 + 3]; if (dd < best) { best = dd; bi = k0 + 3; }
        dd = (vv - 2.f * d4) + ee_s[k0 + 4]; if (dd < best) { best = dd; bi = k0 + 4; }
        dd = (vv - 2.f * d5) + ee_s[k0 + 5]; if (dd < best) { best = dd; bi = k0 + 5; }
        dd = (vv - 2.f * d6) + ee_s[k0 + 6]; if (dd < best) { best = dd; bi = k0 + 6; }
        dd = (vv - 2.f * d7) + ee_s[k0 + 7]; if (dd < best) { best = dd; bi = k0 + 7; }
    }

    // --- heads: quantize = emb[bi]; exact FP order of rounds 1-3 ---
    float lg[ADIM];
#pragma unroll
    for (int a = 0; a < ADIM; ++a) lg[a] = ba[a];
    float val = bv[0];

    const float4* q4 = (const float4*)(emb + (size_t)bi * HDIM);
#pragma unroll
    for (int j4 = 0; j4 < HDIM / 4; ++j4) {
        float4 q = q4[j4];
        const int j = 4 * j4;
#pragma unroll
        for (int a = 0; a < ADIM; ++a) {
            float t = lg[a];
            t = fmaf(q.x, Wa[(j + 0) * ADIM + a], t);
            t = fmaf(q.y, Wa[(j + 1) * ADIM + a], t);
            t = fmaf(q.z, Wa[(j + 2) * ADIM + a], t);
            t = fmaf(q.w, Wa[(j + 3) * ADIM + a], t);
            lg[a] = t;
        }
        val = fmaf(q.x, Wv[j + 0], val);
        val = fmaf(q.y, Wv[j + 1], val);
        val = fmaf(q.z, Wv[j + 2], val);
        val = fmaf(q.w, Wv[j + 3], val);
    }

    float m = lg[0];
#pragma unroll
    for (int a = 1; a < ADIM; ++a) m = fmaxf(m, lg[a]);
    float p[ADIM];
    float s = 0.f;
#pragma unroll
    for (int a = 0; a < ADIM; ++a) { p[a] = __expf(lg[a] - m); s += p[a]; }
    const float inv = 1.f / s;

    float4* outp = (float4*)(out + (size_t)row * ADIM);
    outp[0] = make_float4(p[0] * inv, p[1] * inv, p[2] * inv, p[3] * inv);
    outp[1] = make_float4(p[4] * inv, p[5] * inv, p[6] * inv, p[7] * inv);
    out[(size_t)NROWS * ADIM + row] = val;
}

// ---------------------------------------------------------------------------
extern "C" void kernel_launch(void* const* d_in, const int* in_sizes, int n_in,
                              void* d_out, int out_size, void* d_ws, size_t ws_size,
                              hipStream_t stream) {
    const float* in  = (const float*)d_in[0];
    const float* W1  = (const float*)d_in[1];
    const float* b1  = (const float*)d_in[2];
    const float* Wh  = (const float*)d_in[3];
    const float* bh  = (const float*)d_in[4];
    const float* emb = (const float*)d_in[5];
    const float* Wa  = (const float*)d_in[6];
    const float* ba  = (const float*)d_in[7];
    const float* Wv  = (const float*)d_in[8];
    const float* bv  = (const float*)d_in[9];
    float* out = (float*)d_out;

    const float* w1t = nullptr;
    if (ws_size >= (size_t)SDIM * HDIM * sizeof(float)) {
        w1t_kernel<<<32, 256, 0, stream>>>(W1, (float*)d_ws);
        w1t = (const float*)d_ws;
    }
    fused_kernel<<<NROWS / 256, 256, 0, stream>>>(in, W1, w1t, b1, Wh, bh, emb,
                                                  Wa, ba, Wv, bv, out);
}

// Round 5
// 789.084 us; speedup vs baseline: 2.1160x; 1.2020x over previous
//
#include <hip/hip_runtime.h>
#include <math.h>

#define NROWS 131072
#define SDIM 64
#define HDIM 128
#define KCODES 512
#define ADIM 8

#define R16(M) M(0) M(1) M(2) M(3) M(4) M(5) M(6) M(7) \
               M(8) M(9) M(10) M(11) M(12) M(13) M(14) M(15)
#define R32(M) R16(M) M(16) M(17) M(18) M(19) M(20) M(21) M(22) M(23) \
               M(24) M(25) M(26) M(27) M(28) M(29) M(30) M(31)

// Pin a float4 in VGPRs: empty asm blocks rematerialization/demotion.
#define PIN4(v) asm volatile("" : "+v"(v.x), "+v"(v.y), "+v"(v.z), "+v"(v.w));

// ---------------------------------------------------------------------------
// w1t[t][s] = W1[s][t]  (32 KB) so layer-1 weights are t-major for staging.
// ---------------------------------------------------------------------------
__global__ void w1t_kernel(const float* __restrict__ W1, float* __restrict__ w1t) {
    int i = blockIdx.x * 256 + threadIdx.x;        // 0..8191, == t*64+s
    int t = i >> 6, s = i & 63;
    w1t[i] = W1[s * HDIM + t];
}

// ---------------------------------------------------------------------------
// Main fused kernel. 256 thr/block, 512 blocks, __launch_bounds__(256,2).
// All streamed operands (w1t/Wh/emb) staged to LDS in chunks and read as
// wave-uniform broadcast ds_read_b128 (conflict-free), so the VALU is fed
// without scalar-load latency. FP chain orders identical to rounds 1-4.
// LDS: 24 KB tile + 2 KB ee = 26 KB.
// ---------------------------------------------------------------------------
__global__ __launch_bounds__(256, 2) void fused_lds_kernel(
    const float* __restrict__ in,
    const float* __restrict__ w1t,               // t-major W1 (from ws)
    const float* __restrict__ b1,
    const float* __restrict__ Wh, const float* __restrict__ bh,
    const float* __restrict__ emb,
    const float* __restrict__ Wa, const float* __restrict__ ba,
    const float* __restrict__ Wv, const float* __restrict__ bv,
    float* __restrict__ out)
{
    __shared__ float tile[6144];                  // 24 KB staging buffer
    __shared__ float ee_s[KCODES];                // 2 KB
    const int tid = threadIdx.x;
    const int row = blockIdx.x * 256 + tid;

    // --- ee: 2 codes per thread, exact ee_kernel FP order ---
#pragma unroll
    for (int kk = 0; kk < 2; ++kk) {
        int k = tid + 256 * kk;
        const float* e = emb + k * HDIM;
        float a0 = 0.f, a1 = 0.f, a2 = 0.f, a3 = 0.f;
#pragma unroll
        for (int j = 0; j < HDIM; j += 4) {
            a0 = fmaf(e[j + 0], e[j + 0], a0);
            a1 = fmaf(e[j + 1], e[j + 1], a1);
            a2 = fmaf(e[j + 2], e[j + 2], a2);
            a3 = fmaf(e[j + 3], e[j + 3], a3);
        }
        ee_s[k] = (a0 + a1) + (a2 + a3);
    }

    // --- input row into 16 named float4s, pinned ---
    const float4* inr4 = (const float4*)(in + (size_t)row * SDIM);
#define DECLI(n) float4 i##n = inr4[n]; PIN4(i##n)
    R16(DECLI)

    // --- x2 accumulators: 32 named float4s, init = bh ---
#define DECLX(m) float4 x##m = make_float4(bh[4*(m)+0], bh[4*(m)+1], bh[4*(m)+2], bh[4*(m)+3]);
    R32(DECLX)

#define L1T(n) xt = fmaf(i##n.x, wr[4*(n)+0], xt); xt = fmaf(i##n.y, wr[4*(n)+1], xt); \
               xt = fmaf(i##n.z, wr[4*(n)+2], xt); xt = fmaf(i##n.w, wr[4*(n)+3], xt);
#define L2(m)  x##m.x = fmaf(xt, whr[4*(m)+0], x##m.x); x##m.y = fmaf(xt, whr[4*(m)+1], x##m.y); \
               x##m.z = fmaf(xt, whr[4*(m)+2], x##m.z); x##m.w = fmaf(xt, whr[4*(m)+3], x##m.w);

    // --- fused layer1+layer2 in 4 chunks of 32 t ---
    // tile layout per chunk: [0..2047] w1t rows (32 x 64), [2048..6143] Wh rows (32 x 128)
    for (int tc = 0; tc < 4; ++tc) {
        __syncthreads();                                   // prev chunk consumed
        {
            const float4* s1 = (const float4*)(w1t + tc * 32 * SDIM);
#pragma unroll
            for (int u = 0; u < 2; ++u)
                ((float4*)tile)[tid + 256 * u] = s1[tid + 256 * u];
            const float4* s2 = (const float4*)(Wh + tc * 32 * HDIM);
#pragma unroll
            for (int u = 0; u < 4; ++u)
                ((float4*)(tile + 2048))[tid + 256 * u] = s2[tid + 256 * u];
        }
        __syncthreads();
        for (int tl = 0; tl < 32; ++tl) {
            const int t = tc * 32 + tl;
            float xt = b1[t];
            const float* wr = tile + tl * SDIM;            // broadcast b128 reads
            R16(L1T)
            xt = fmaxf(xt, 0.f);                           // relu(x1[t])
            const float* whr = tile + 2048 + tl * HDIM;    // broadcast b128 reads
            R32(L2)
        }
    }

    // --- relu(x2), pinned ---
#define RELUX(m) x##m.x = fmaxf(x##m.x, 0.f); x##m.y = fmaxf(x##m.y, 0.f); \
                 x##m.z = fmaxf(x##m.z, 0.f); x##m.w = fmaxf(x##m.w, 0.f); PIN4(x##m)
    R32(RELUX)

    // --- vv = ||x||^2, 4-way split by j%4 (exact round-1..4 order) ---
    float v0 = 0.f, v1 = 0.f, v2 = 0.f, v3 = 0.f;
#define VV(m) v0 = fmaf(x##m.x, x##m.x, v0); v1 = fmaf(x##m.y, x##m.y, v1); \
              v2 = fmaf(x##m.z, x##m.z, v2); v3 = fmaf(x##m.w, x##m.w, v3);
    R32(VV)
    const float vv = (v0 + v1) + (v2 + v3);

    // --- VQ scoring: 16 chunks of 32 codes staged to LDS; 8 codes/group ---
    float best = 3.402823466e38f;
    int bi = 0;
#define SC(m) \
    d0 = fmaf(x##m.x, eb[0*HDIM+4*(m)+0], d0); d0 = fmaf(x##m.y, eb[0*HDIM+4*(m)+1], d0); \
    d0 = fmaf(x##m.z, eb[0*HDIM+4*(m)+2], d0); d0 = fmaf(x##m.w, eb[0*HDIM+4*(m)+3], d0); \
    d1 = fmaf(x##m.x, eb[1*HDIM+4*(m)+0], d1); d1 = fmaf(x##m.y, eb[1*HDIM+4*(m)+1], d1); \
    d1 = fmaf(x##m.z, eb[1*HDIM+4*(m)+2], d1); d1 = fmaf(x##m.w, eb[1*HDIM+4*(m)+3], d1); \
    d2 = fmaf(x##m.x, eb[2*HDIM+4*(m)+0], d2); d2 = fmaf(x##m.y, eb[2*HDIM+4*(m)+1], d2); \
    d2 = fmaf(x##m.z, eb[2*HDIM+4*(m)+2], d2); d2 = fmaf(x##m.w, eb[2*HDIM+4*(m)+3], d2); \
    d3 = fmaf(x##m.x, eb[3*HDIM+4*(m)+0], d3); d3 = fmaf(x##m.y, eb[3*HDIM+4*(m)+1], d3); \
    d3 = fmaf(x##m.z, eb[3*HDIM+4*(m)+2], d3); d3 = fmaf(x##m.w, eb[3*HDIM+4*(m)+3], d3); \
    d4 = fmaf(x##m.x, eb[4*HDIM+4*(m)+0], d4); d4 = fmaf(x##m.y, eb[4*HDIM+4*(m)+1], d4); \
    d4 = fmaf(x##m.z, eb[4*HDIM+4*(m)+2], d4); d4 = fmaf(x##m.w, eb[4*HDIM+4*(m)+3], d4); \
    d5 = fmaf(x##m.x, eb[5*HDIM+4*(m)+0], d5); d5 = fmaf(x##m.y, eb[5*HDIM+4*(m)+1], d5); \
    d5 = fmaf(x##m.z, eb[5*HDIM+4*(m)+2], d5); d5 = fmaf(x##m.w, eb[5*HDIM+4*(m)+3], d5); \
    d6 = fmaf(x##m.x, eb[6*HDIM+4*(m)+0], d6); d6 = fmaf(x##m.y, eb[6*HDIM+4*(m)+1], d6); \
    d6 = fmaf(x##m.z, eb[6*HDIM+4*(m)+2], d6); d6 = fmaf(x##m.w, eb[6*HDIM+4*(m)+3], d6); \
    d7 = fmaf(x##m.x, eb[7*HDIM+4*(m)+0], d7); d7 = fmaf(x##m.y, eb[7*HDIM+4*(m)+1], d7); \
    d7 = fmaf(x##m.z, eb[7*HDIM+4*(m)+2], d7); d7 = fmaf(x##m.w, eb[7*HDIM+4*(m)+3], d7);

    for (int kc = 0; kc < 16; ++kc) {
        __syncthreads();                                   // prev chunk consumed
        {
            const float4* se = (const float4*)(emb + (size_t)kc * 32 * HDIM);
#pragma unroll
            for (int u = 0; u < 4; ++u)
                ((float4*)tile)[tid + 256 * u] = se[tid + 256 * u];
        }
        __syncthreads();
        for (int g = 0; g < 4; ++g) {
            const int k0 = kc * 32 + g * 8;
            const float* eb = tile + g * 8 * HDIM;         // broadcast b128 reads
            float d0 = 0.f, d1 = 0.f, d2 = 0.f, d3 = 0.f;
            float d4 = 0.f, d5 = 0.f, d6 = 0.f, d7 = 0.f;
            R32(SC)
            float dd;
            dd = (vv - 2.f * d0) + ee_s[k0 + 0]; if (dd < best) { best = dd; bi = k0 + 0; }
            dd = (vv - 2.f * d1) + ee_s[k0 + 1]; if (dd < best) { best = dd; bi = k0 + 1; }
            dd = (vv - 2.f * d2) + ee_s[k0 + 2]; if (dd < best) { best = dd; bi = k0 + 2; }
            dd = (vv - 2.f * d3) + ee_s[k0 + 3]; if (dd < best) { best = dd; bi = k0 + 3; }
            dd = (vv - 2.f * d4) + ee_s[k0 + 4]; if (dd < best) { best = dd; bi = k0 + 4; }
            dd = (vv - 2.f * d5) + ee_s[k0 + 5]; if (dd < best) { best = dd; bi = k0 + 5; }
            dd = (vv - 2.f * d6) + ee_s[k0 + 6]; if (dd < best) { best = dd; bi = k0 + 6; }
            dd = (vv - 2.f * d7) + ee_s[k0 + 7]; if (dd < best) { best = dd; bi = k0 + 7; }
        }
    }

    // --- heads: quantize = emb[bi]; exact FP order of rounds 1-4 ---
    float lg[ADIM];
#pragma unroll
    for (int a = 0; a < ADIM; ++a) lg[a] = ba[a];
    float val = bv[0];

    const float4* q4 = (const float4*)(emb + (size_t)bi * HDIM);
#pragma unroll
    for (int j4 = 0; j4 < HDIM / 4; ++j4) {
        float4 q = q4[j4];
        const int j = 4 * j4;
#pragma unroll
        for (int a = 0; a < ADIM; ++a) {
            float t = lg[a];
            t = fmaf(q.x, Wa[(j + 0) * ADIM + a], t);
            t = fmaf(q.y, Wa[(j + 1) * ADIM + a], t);
            t = fmaf(q.z, Wa[(j + 2) * ADIM + a], t);
            t = fmaf(q.w, Wa[(j + 3) * ADIM + a], t);
            lg[a] = t;
        }
        val = fmaf(q.x, Wv[j + 0], val);
        val = fmaf(q.y, Wv[j + 1], val);
        val = fmaf(q.z, Wv[j + 2], val);
        val = fmaf(q.w, Wv[j + 3], val);
    }

    float m = lg[0];
#pragma unroll
    for (int a = 1; a < ADIM; ++a) m = fmaxf(m, lg[a]);
    float p[ADIM];
    float s = 0.f;
#pragma unroll
    for (int a = 0; a < ADIM; ++a) { p[a] = __expf(lg[a] - m); s += p[a]; }
    const float inv = 1.f / s;

    float4* outp = (float4*)(out + (size_t)row * ADIM);
    outp[0] = make_float4(p[0] * inv, p[1] * inv, p[2] * inv, p[3] * inv);
    outp[1] = make_float4(p[4] * inv, p[5] * inv, p[6] * inv, p[7] * inv);
    out[(size_t)NROWS * ADIM + row] = val;
}

// ---------------------------------------------------------------------------
// Fallback (no workspace): round-4 global-feed version, correct but slower.
// ---------------------------------------------------------------------------
__global__ __launch_bounds__(256, 2) void fused_global_kernel(
    const float* __restrict__ in,
    const float* __restrict__ W1, const float* __restrict__ b1,
    const float* __restrict__ Wh, const float* __restrict__ bh,
    const float* __restrict__ emb,
    const float* __restrict__ Wa, const float* __restrict__ ba,
    const float* __restrict__ Wv, const float* __restrict__ bv,
    float* __restrict__ out)
{
    __shared__ float ee_s[KCODES];
    const int tid = threadIdx.x;
    const int row = blockIdx.x * 256 + tid;

#pragma unroll
    for (int kk = 0; kk < 2; ++kk) {
        int k = tid + 256 * kk;
        const float* e = emb + k * HDIM;
        float a0 = 0.f, a1 = 0.f, a2 = 0.f, a3 = 0.f;
#pragma unroll
        for (int j = 0; j < HDIM; j += 4) {
            a0 = fmaf(e[j + 0], e[j + 0], a0);
            a1 = fmaf(e[j + 1], e[j + 1], a1);
            a2 = fmaf(e[j + 2], e[j + 2], a2);
            a3 = fmaf(e[j + 3], e[j + 3], a3);
        }
        ee_s[k] = (a0 + a1) + (a2 + a3);
    }
    __syncthreads();

    const float4* inr4 = (const float4*)(in + (size_t)row * SDIM);
#define DECLI2(n) float4 i##n = inr4[n]; PIN4(i##n)
    R16(DECLI2)
    R32(DECLX)

#define L1N(n) xt = fmaf(i##n.x, wc[(4*(n)+0)*HDIM], xt); xt = fmaf(i##n.y, wc[(4*(n)+1)*HDIM], xt); \
               xt = fmaf(i##n.z, wc[(4*(n)+2)*HDIM], xt); xt = fmaf(i##n.w, wc[(4*(n)+3)*HDIM], xt);
    for (int t = 0; t < HDIM; ++t) {
        float xt = b1[t];
        const float* wc = W1 + t;
        R16(L1N)
        xt = fmaxf(xt, 0.f);
        const float* whr = Wh + t * HDIM;
        R32(L2)
    }
    R32(RELUX)

    float v0 = 0.f, v1 = 0.f, v2 = 0.f, v3 = 0.f;
    R32(VV)
    const float vv = (v0 + v1) + (v2 + v3);

    float best = 3.402823466e38f;
    int bi = 0;
    for (int k0 = 0; k0 < KCODES; k0 += 8) {
        const float* eb = emb + (size_t)k0 * HDIM;
        float d0 = 0.f, d1 = 0.f, d2 = 0.f, d3 = 0.f;
        float d4 = 0.f, d5 = 0.f, d6 = 0.f, d7 = 0.f;
        R32(SC)
        float dd;
        dd = (vv - 2.f * d0) + ee_s[k0 + 0]; if (dd < best) { best = dd; bi = k0 + 0; }
        dd = (vv - 2.f * d1) + ee_s[k0 + 1]; if (dd < best) { best = dd; bi = k0 + 1; }
        dd = (vv - 2.f * d2) + ee_s[k0 + 2]; if (dd < best) { best = dd; bi = k0 + 2; }
        dd = (vv - 2.f * d3) + ee_s[k0 + 3]; if (dd < best) { best = dd; bi = k0 + 3; }
        dd = (vv - 2.f * d4) + ee_s[k0 + 4]; if (dd < best) { best = dd; bi = k0 + 4; }
        dd = (vv - 2.f * d5) + ee_s[k0 + 5]; if (dd < best) { best = dd; bi = k0 + 5; }
        dd = (vv - 2.f * d6) + ee_s[k0 + 6]; if (dd < best) { best = dd; bi = k0 + 6; }
        dd = (vv - 2.f * d7) + ee_s[k0 + 7]; if (dd < best) { best = dd; bi = k0 + 7; }
    }

    float lg[ADIM];
#pragma unroll
    for (int a = 0; a < ADIM; ++a) lg[a] = ba[a];
    float val = bv[0];
    const float4* q4 = (const float4*)(emb + (size_t)bi * HDIM);
#pragma unroll
    for (int j4 = 0; j4 < HDIM / 4; ++j4) {
        float4 q = q4[j4];
        const int j = 4 * j4;
#pragma unroll
        for (int a = 0; a < ADIM; ++a) {
            float t = lg[a];
            t = fmaf(q.x, Wa[(j + 0) * ADIM + a], t);
            t = fmaf(q.y, Wa[(j + 1) * ADIM + a], t);
            t = fmaf(q.z, Wa[(j + 2) * ADIM + a], t);
            t = fmaf(q.w, Wa[(j + 3) * ADIM + a], t);
            lg[a] = t;
        }
        val = fmaf(q.x, Wv[j + 0], val);
        val = fmaf(q.y, Wv[j + 1], val);
        val = fmaf(q.z, Wv[j + 2], val);
        val = fmaf(q.w, Wv[j + 3], val);
    }
    float m = lg[0];
#pragma unroll
    for (int a = 1; a < ADIM; ++a) m = fmaxf(m, lg[a]);
    float p[ADIM];
    float s = 0.f;
#pragma unroll
    for (int a = 0; a < ADIM; ++a) { p[a] = __expf(lg[a] - m); s += p[a]; }
    const float inv = 1.f / s;
    float4* outp = (float4*)(out + (size_t)row * ADIM);
    outp[0] = make_float4(p[0] * inv, p[1] * inv, p[2] * inv, p[3] * inv);
    outp[1] = make_float4(p[4] * inv, p[5] * inv, p[6] * inv, p[7] * inv);
    out[(size_t)NROWS * ADIM + row] = val;
}

// ---------------------------------------------------------------------------
extern "C" void kernel_launch(void* const* d_in, const int* in_sizes, int n_in,
                              void* d_out, int out_size, void* d_ws, size_t ws_size,
                              hipStream_t stream) {
    const float* in  = (const float*)d_in[0];
    const float* W1  = (const float*)d_in[1];
    const float* b1  = (const float*)d_in[2];
    const float* Wh  = (const float*)d_in[3];
    const float* bh  = (const float*)d_in[4];
    const float* emb = (const float*)d_in[5];
    const float* Wa  = (const float*)d_in[6];
    const float* ba  = (const float*)d_in[7];
    const float* Wv  = (const float*)d_in[8];
    const float* bv  = (const float*)d_in[9];
    float* out = (float*)d_out;

    if (ws_size >= (size_t)SDIM * HDIM * sizeof(float)) {
        float* w1t = (float*)d_ws;
        w1t_kernel<<<32, 256, 0, stream>>>(W1, w1t);
        fused_lds_kernel<<<NROWS / 256, 256, 0, stream>>>(in, w1t, b1, Wh, bh, emb,
                                                          Wa, ba, Wv, bv, out);
    } else {
        fused_global_kernel<<<NROWS / 256, 256, 0, stream>>>(in, W1, b1, Wh, bh, emb,
                                                             Wa, ba, Wv, bv, out);
    }
}